// Round 3
// baseline (312.683 us; speedup 1.0000x reference)
//
#include <hip/hip_runtime.h>
#include <stdint.h>

// ---------------------------------------------------------------------------
// Bit-exact replica of XLA:CPU's f32 exp (GenerateVF32Exp, Cephes/Eigen pexp)
// AS COMPILED BY THE XLA CPU BACKEND: TargetOptions.AllowFPOpFusion == Fast
// fuses every single-use fmul feeding an fadd/fsub into one x86 FMA.
// gfx950 v_fma_f32 == x86 vfmadd (IEEE single rounding): mirror exactly.
// ---------------------------------------------------------------------------
__device__ __forceinline__ float xla_cpu_expf_fused(float x) {
#pragma clang fp contract(off)
  const float exp_hi = 88.3762626647950f;
  const float exp_lo = -88.3762626647949f;
  const float log2ef = 1.44269504088896341f;
  const float c1 = 0.693359375f;
  const float c2 = -2.12194440e-4f;
  const float p0 = 1.9875691500e-4f;
  const float p1 = 1.3981999507e-3f;
  const float p2 = 8.3334519073e-3f;
  const float p3 = 4.1665795894e-2f;
  const float p4 = 1.6666665459e-1f;
  const float p5 = 5.0000001201e-1f;

  // vsl.Clamp(input, lo, hi)
  float xc = fminf(fmaxf(x, exp_lo), exp_hi);

  // fx = floor(fma(xc, log2e, 0.5))            [fadd(fmul) -> vfmadd]
  float fx = floorf(__builtin_fmaf(xc, log2ef, 0.5f));

  // x = xc - c1*fx ; x = x - c2*fx             [fsub(a, fmul) -> vfnmadd]
  float xr = __builtin_fmaf(-c1, fx, xc);
  xr = __builtin_fmaf(-c2, fx, xr);

  float z2 = xr * xr;                           // plain fmul (fma operand)
  float y = __builtin_fmaf(xr, p0, p1);         // MulAdd chain, fused
  y = __builtin_fmaf(y, xr, p2);
  y = __builtin_fmaf(y, xr, p3);
  y = __builtin_fmaf(y, xr, p4);
  y = __builtin_fmaf(y, xr, p5);
  y = __builtin_fmaf(y, z2, xr);
  y = 1.0f + y;                                 // plain fadd

  int n = (int)fx;                              // fptosi (fx integral)
  float p2n = __int_as_float((n + 127) << 23);
  float res = y * p2n;                          // plain fmul (feeds max)
  return fmaxf(res, x);                         // Max(result, ORIGINAL input)
}

// LogisticExpander: sigmoid(v) = 1/(1+exp(-v)); strict IEEE neg/add/div/mul.
__device__ __forceinline__ float silu_ref(float v) {
#pragma clang fp contract(off)
  float t = xla_cpu_expf_fused(-v);
  float s = 1.0f / (1.0f + t);   // IEEE correctly-rounded divide on gfx950
  return v * s;
}

// One f32 value == 32 contiguous pulse floats (MSB first).
// Pulse floats are exactly 0.0f (0x00000000) or 1.0f (0x3F800000):
// the bit test is (word != 0).  [Round-1/2 bug: used bit 30, which is 0
// for 1.0f -> everything decoded to 0.]
__global__ __launch_bounds__(256) void spike_silu_kernel(
    const uint32_t* __restrict__ in, uint32_t* __restrict__ out, int nvals) {
  const int stride = gridDim.x * blockDim.x;
  for (int i = blockIdx.x * blockDim.x + threadIdx.x; i < nvals; i += stride) {
    const uint4* pin = reinterpret_cast<const uint4*>(in) + (size_t)i * 8;
    uint4 w[8];
#pragma unroll
    for (int q = 0; q < 8; ++q) w[q] = pin[q];

    uint32_t u = 0;
#pragma unroll
    for (int q = 0; q < 8; ++q) {
      u |= (w[q].x != 0u ? 1u : 0u) << (31 - 4 * q);
      u |= (w[q].y != 0u ? 1u : 0u) << (30 - 4 * q);
      u |= (w[q].z != 0u ? 1u : 0u) << (29 - 4 * q);
      u |= (w[q].w != 0u ? 1u : 0u) << (28 - 4 * q);
    }

    const float v = __uint_as_float(u);
    const uint32_t ru = __float_as_uint(silu_ref(v));

    uint4* pout = reinterpret_cast<uint4*>(out) + (size_t)i * 8;
#pragma unroll
    for (int q = 0; q < 8; ++q) {
      uint4 o;
      o.x = ((ru >> (31 - 4 * q)) & 1u) ? 0x3F800000u : 0u;
      o.y = ((ru >> (30 - 4 * q)) & 1u) ? 0x3F800000u : 0u;
      o.z = ((ru >> (29 - 4 * q)) & 1u) ? 0x3F800000u : 0u;
      o.w = ((ru >> (28 - 4 * q)) & 1u) ? 0x3F800000u : 0u;
      pout[q] = o;
    }
  }
}

extern "C" void kernel_launch(void* const* d_in, const int* in_sizes, int n_in,
                              void* d_out, int out_size, void* d_ws, size_t ws_size,
                              hipStream_t stream) {
  (void)in_sizes; (void)n_in; (void)d_ws; (void)ws_size;
  const uint32_t* in = reinterpret_cast<const uint32_t*>(d_in[0]);
  uint32_t* out = reinterpret_cast<uint32_t*>(d_out);
  const int nvals = out_size / 32;  // 2048*2048 = 4,194,304 values

  const int threads = 256;
  const int blocks = 2048;  // grid-stride: 8 values/thread
  spike_silu_kernel<<<blocks, threads, 0, stream>>>(in, out, nvals);
}

// Round 4
// 208.469 us; speedup vs baseline: 1.4999x; 1.4999x over previous
//
#include <hip/hip_runtime.h>
#include <stdint.h>

// ---------------------------------------------------------------------------
// Bit-exact replica of XLA:CPU's f32 exp (GenerateVF32Exp, Cephes/Eigen pexp)
// as compiled with TargetOptions.AllowFPOpFusion == Fast (x86 FMA fusion).
// gfx950 v_fma_f32 == x86 vfmadd (IEEE single rounding). VERIFIED bit-exact
// in round 3 (absmax 0.0) — do not modify.
// ---------------------------------------------------------------------------
__device__ __forceinline__ float xla_cpu_expf_fused(float x) {
#pragma clang fp contract(off)
  const float exp_hi = 88.3762626647950f;
  const float exp_lo = -88.3762626647949f;
  const float log2ef = 1.44269504088896341f;
  const float c1 = 0.693359375f;
  const float c2 = -2.12194440e-4f;
  const float p0 = 1.9875691500e-4f;
  const float p1 = 1.3981999507e-3f;
  const float p2 = 8.3334519073e-3f;
  const float p3 = 4.1665795894e-2f;
  const float p4 = 1.6666665459e-1f;
  const float p5 = 5.0000001201e-1f;

  float xc = fminf(fmaxf(x, exp_lo), exp_hi);
  float fx = floorf(__builtin_fmaf(xc, log2ef, 0.5f));
  float xr = __builtin_fmaf(-c1, fx, xc);
  xr = __builtin_fmaf(-c2, fx, xr);

  float z2 = xr * xr;
  float y = __builtin_fmaf(xr, p0, p1);
  y = __builtin_fmaf(y, xr, p2);
  y = __builtin_fmaf(y, xr, p3);
  y = __builtin_fmaf(y, xr, p4);
  y = __builtin_fmaf(y, xr, p5);
  y = __builtin_fmaf(y, z2, xr);
  y = 1.0f + y;

  int n = (int)fx;
  float p2n = __int_as_float((n + 127) << 23);
  float res = y * p2n;
  return fmaxf(res, x);
}

__device__ __forceinline__ float silu_ref(float v) {
#pragma clang fp contract(off)
  float t = xla_cpu_expf_fused(-v);
  float s = 1.0f / (1.0f + t);   // IEEE correctly-rounded divide
  return v * s;
}

// ---------------------------------------------------------------------------
// Coalesced layout: lane L of a wave loads uint4 index (base + L) — the wave
// covers 1 KB contiguous = 256 pulse words = 8 values. Each aligned 8-lane
// group owns one value: lane packs its 4 pulses into a nibble at value-bit
// position (28 - 4*(lane&7)), then a 3-round shfl_xor OR-butterfly assembles
// the full 32-bit word in every lane of the group. silu is computed
// redundantly by all 8 lanes (VALU was 7% busy — free). Store is the exact
// inverse: each lane emits its own nibble as 4 pulse floats -> own uint4.
// ---------------------------------------------------------------------------
__global__ __launch_bounds__(256) void spike_silu_kernel(
    const uint4* __restrict__ in, uint4* __restrict__ out, int n4) {
  const int stride = gridDim.x * blockDim.x;
  const int sh = 28 - 4 * (threadIdx.x & 7);  // value-bit shift for this lane

  for (int i = blockIdx.x * blockDim.x + threadIdx.x; i < n4; i += stride) {
    uint4 w = in[i];

    // pulses are exactly 0x00000000 or 0x3F800000 -> bit = (word != 0)
    uint32_t nib = ((w.x != 0u) ? 8u : 0u) | ((w.y != 0u) ? 4u : 0u) |
                   ((w.z != 0u) ? 2u : 0u) | ((w.w != 0u) ? 1u : 0u);
    uint32_t u = nib << sh;

    // OR-butterfly across the aligned 8-lane group (xor 1,2,4)
    u |= (uint32_t)__shfl_xor((int)u, 1);
    u |= (uint32_t)__shfl_xor((int)u, 2);
    u |= (uint32_t)__shfl_xor((int)u, 4);

    const float v = __uint_as_float(u);
    const uint32_t ru = __float_as_uint(silu_ref(v));

    const uint32_t nib4 = (ru >> sh) & 0xFu;
    uint4 o;
    o.x = (nib4 & 8u) ? 0x3F800000u : 0u;
    o.y = (nib4 & 4u) ? 0x3F800000u : 0u;
    o.z = (nib4 & 2u) ? 0x3F800000u : 0u;
    o.w = (nib4 & 1u) ? 0x3F800000u : 0u;
    out[i] = o;
  }
}

extern "C" void kernel_launch(void* const* d_in, const int* in_sizes, int n_in,
                              void* d_out, int out_size, void* d_ws, size_t ws_size,
                              hipStream_t stream) {
  (void)in_sizes; (void)n_in; (void)d_ws; (void)ws_size;
  const uint4* in = reinterpret_cast<const uint4*>(d_in[0]);
  uint4* out = reinterpret_cast<uint4*>(d_out);
  const int n4 = out_size / 4;  // 33,554,432 uint4s (16B each)

  const int threads = 256;
  const int blocks = 2048;  // grid-stride, 8 blocks/CU, 64 iters/thread
  spike_silu_kernel<<<blocks, threads, 0, stream>>>(in, out, n4);
}